// Round 21
// baseline (210.442 us; speedup 1.0000x reference)
//
#include <hip/hip_runtime.h>
#include <hip/hip_bf16.h>

// ---------------------------------------------------------------------------
// GCN 2-layer + edge dot logits, CSR-pull aggregation.
// agg[d] = dinv[d] * ( sum_{s in in(d)} hs[s] + hs[d] ) + b,  hs = (A@W)*dinv[row]
// Round 21: r20 + cnt_rank at 1 edge/thread (grid 3125 -> full occupancy; the
// 45.6us top dispatch was latency-starved at 3 blocks/CU). Structure otherwise:
// XCD-chunked tables [c][*][16] (slices pinned to XCD L2), padded x8 CSR with
// uint4 ushort index loads, atomic-free fill via rank[], chunked agg1T
// (coalesced pull writes, gemm2 reads chunks natively), edge-order logits.
// ---------------------------------------------------------------------------

using ushort_t = unsigned short;

// count + per-edge rank within its dst segment; 1 edge/thread for occupancy
__global__ void cnt_rank_k(const int* __restrict__ dst, int* __restrict__ cnt,
                           int* __restrict__ rank, int E) {
    int e = blockIdx.x * blockDim.x + threadIdx.x;
    if (e < E) rank[e] = atomicAdd(&cnt[dst[e]], 1);
}

// block scan over PADDED counts ((deg+7)&~7)
__global__ void scan1_k(const int* __restrict__ cnt, int* __restrict__ incl,
                        int* __restrict__ bsum, int N) {
    __shared__ int sh[256];
    int i = blockIdx.x * 256 + threadIdx.x;
    int v = (i < N) ? ((cnt[i] + 7) & ~7) : 0;
    sh[threadIdx.x] = v;
    __syncthreads();
#pragma unroll
    for (int off = 1; off < 256; off <<= 1) {
        int t = (threadIdx.x >= off) ? sh[threadIdx.x - off] : 0;
        __syncthreads();
        sh[threadIdx.x] += t;
        __syncthreads();
    }
    if (i < N) incl[i] = sh[threadIdx.x];
    if (threadIdx.x == 255) bsum[blockIdx.x] = sh[255];
}

// fused scan2+scan3: rowptr (padded), dinv, pad-filler colu entries, rowptr[N].
__global__ __launch_bounds__(256) void scan23_k(const int* __restrict__ cnt,
                                                const int* __restrict__ incl,
                                                const int* __restrict__ bsum,
                                                int* __restrict__ rowptr,
                                                float* __restrict__ dinv,
                                                ushort_t* __restrict__ colu,
                                                int N, int NB) {
    __shared__ int sh[256];
    __shared__ int blockOff, totalPad;
    int v = (threadIdx.x < NB) ? bsum[threadIdx.x] : 0;
    sh[threadIdx.x] = v;
    __syncthreads();
#pragma unroll
    for (int off = 1; off < 256; off <<= 1) {
        int t = (threadIdx.x >= off) ? sh[threadIdx.x - off] : 0;
        __syncthreads();
        sh[threadIdx.x] += t;
        __syncthreads();
    }
    if (threadIdx.x == blockIdx.x) blockOff = sh[threadIdx.x] - v;  // exclusive
    if (threadIdx.x == NB - 1) totalPad = sh[threadIdx.x];          // grand total
    __syncthreads();
    int i = blockIdx.x * 256 + threadIdx.x;
    if (i < N) {
        int c = cnt[i];
        int cp = (c + 7) & ~7;
        int excl = incl[i] - cp + blockOff;
        rowptr[i] = excl;
        dinv[i] = rsqrtf(1.0f + (float)c);  // +1 self-loop
        for (int k = c; k < cp; k++) colu[excl + k] = (ushort_t)N;  // filler
    }
    if (i == 0) rowptr[N] = totalPad;
}

// ---------------------------------------------------------------------------
// GEMM body, BM=32, BK=16, 256 threads (conflict-free LDS maps).
// A input: linear [M][128] (CA=false) or chunked [8][Na][16] (CA=true).
// Output CHUNK-TRANSPOSED: OutT[chunk][Np][16].
// ---------------------------------------------------------------------------
template <int BN, bool RELU, bool CA>
__device__ __forceinline__ void gemm_body32(const float* __restrict__ A,
                                            const float* __restrict__ W,
                                            const float* __restrict__ dscale,
                                            float4* __restrict__ OutT,
                                            int M, int Np, int Na, int row0,
                                            float (*As)[36], float (*Bs)[BN]) {
    constexpr int K = 128, BK = 16;
    constexpr int TN = BN / 16;  // 8 (BN=128) or 4 (BN=64)
    const int tid = threadIdx.x;
    const int tx = tid & 15, ty = tid >> 4;

    float acc[2][TN];
#pragma unroll
    for (int m = 0; m < 2; m++)
#pragma unroll
        for (int n = 0; n < TN; n++) acc[m][n] = 0.0f;

    for (int kt = 0; kt < K; kt += BK) {
        if (tid < 128) {
            int r = tid >> 2;
            int kq = (tid & 3) * 4;
            float4 av = make_float4(0.f, 0.f, 0.f, 0.f);
            int gr = row0 + r;
            if (gr < M) {
                if (CA)
                    av = *reinterpret_cast<const float4*>(
                        A + ((size_t)(kt >> 4) * Na + gr) * 16 + kq);
                else
                    av = *reinterpret_cast<const float4*>(A + (size_t)gr * K + kt + kq);
            }
            if (RELU) {
                av.x = fmaxf(av.x, 0.f); av.y = fmaxf(av.y, 0.f);
                av.z = fmaxf(av.z, 0.f); av.w = fmaxf(av.w, 0.f);
            }
            As[kq + 0][r] = av.x; As[kq + 1][r] = av.y;
            As[kq + 2][r] = av.z; As[kq + 3][r] = av.w;
        }
#pragma unroll
        for (int s = 0; s < (BK * BN) / (256 * 4); s++) {
            int f = s * 256 + tid;
            int brow = f / (BN / 4);
            int bcol = (f % (BN / 4)) * 4;
            float4 bv = *reinterpret_cast<const float4*>(W + (size_t)(kt + brow) * BN + bcol);
            *reinterpret_cast<float4*>(&Bs[brow][bcol]) = bv;
        }
        __syncthreads();

#pragma unroll
        for (int k = 0; k < BK; k++) {
            float2 a2 = *reinterpret_cast<const float2*>(&As[k][ty * 2]);
            float a[2] = {a2.x, a2.y};
            float b[TN];
            float4 b0 = *reinterpret_cast<const float4*>(&Bs[k][tx * 4]);
            b[0] = b0.x; b[1] = b0.y; b[2] = b0.z; b[3] = b0.w;
            if (TN == 8) {
                float4 b1 = *reinterpret_cast<const float4*>(&Bs[k][64 + tx * 4]);
                b[4] = b1.x; b[5] = b1.y; b[6] = b1.z; b[7] = b1.w;
            }
#pragma unroll
            for (int m = 0; m < 2; m++)
#pragma unroll
                for (int n = 0; n < TN; n++) acc[m][n] = fmaf(a[m], b[n], acc[m][n]);
        }
        __syncthreads();
    }

    const int chunk0 = tx >> 2;
    const int off = tx & 3;
#pragma unroll
    for (int m = 0; m < 2; m++) {
        int gr = row0 + ty * 2 + m;
        if (gr < M) {
            float dv = dscale[gr];
            float4 o0 = make_float4(acc[m][0] * dv, acc[m][1] * dv,
                                    acc[m][2] * dv, acc[m][3] * dv);
            OutT[((size_t)chunk0 * Np + gr) * 4 + off] = o0;
            if (TN == 8) {
                float4 o1 = make_float4(acc[m][4] * dv, acc[m][5] * dv,
                                        acc[m][6] * dv, acc[m][7] * dv);
                OutT[((size_t)(4 + chunk0) * Np + gr) * 4 + off] = o1;
            }
        }
    }
}

// ---------------------------------------------------------------------------
// FUSED: blocks [0,gemmBlocks) = GEMM1 -> hsT chunked (+ block 0 zeroes filler
// row N); rest = atomic-free CSR fill: colu[rowptr[dst]+rank] = (ushort)src.
// ---------------------------------------------------------------------------
__global__ __launch_bounds__(256) void gemm1_fill_k(const float* __restrict__ A,
                                                    const float* __restrict__ W,
                                                    const float* __restrict__ dscale,
                                                    float4* __restrict__ OutT,
                                                    int M, int Np,
                                                    const int* __restrict__ src,
                                                    const int* __restrict__ dst,
                                                    const int* __restrict__ rowptr,
                                                    const int* __restrict__ rank,
                                                    ushort_t* __restrict__ colu, int E,
                                                    int gemmBlocks) {
    __shared__ float As[16][36];
    __shared__ float Bs[16][128];
    int g = (int)blockIdx.x;
    if (g >= gemmBlocks) {
        int t = (g - gemmBlocks) * 256 + threadIdx.x;
        int e = t * 4;
        if (e + 4 <= E) {
            int4 s4 = *reinterpret_cast<const int4*>(src + e);
            int4 d4 = *reinterpret_cast<const int4*>(dst + e);
            int4 r4 = *reinterpret_cast<const int4*>(rank + e);
            colu[rowptr[d4.x] + r4.x] = (ushort_t)s4.x;
            colu[rowptr[d4.y] + r4.y] = (ushort_t)s4.y;
            colu[rowptr[d4.z] + r4.z] = (ushort_t)s4.z;
            colu[rowptr[d4.w] + r4.w] = (ushort_t)s4.w;
        } else {
            for (int i = e; i < E; i++)
                colu[rowptr[dst[i]] + rank[i]] = (ushort_t)src[i];
        }
        return;
    }
    if (g == 0 && threadIdx.x < 32) {  // zero filler row N of all 8 chunks
        int c = threadIdx.x >> 2, q4 = threadIdx.x & 3;
        OutT[((size_t)c * Np + (Np - 1)) * 4 + q4] = make_float4(0.f, 0.f, 0.f, 0.f);
    }
    gemm_body32<128, false, false>(A, W, dscale, OutT, M, Np, 0, g * 32, As, Bs);
}

// gemm2: A = agg1T chunked [8][N][16] (relu'd on load); out g2T chunked [4][Np][16].
__global__ __launch_bounds__(256) void gemm2_k(const float* __restrict__ AT,
                                               const float* __restrict__ W,
                                               const float* __restrict__ dscale,
                                               float4* __restrict__ OutT,
                                               int M, int Np, int Na) {
    __shared__ float As[16][36];
    __shared__ float Bs[16][64];
    if (blockIdx.x == 0 && threadIdx.x < 16) {  // zero filler row of 4 chunks
        int c = threadIdx.x >> 2, q4 = threadIdx.x & 3;
        OutT[((size_t)c * Np + (Np - 1)) * 4 + q4] = make_float4(0.f, 0.f, 0.f, 0.f);
    }
    gemm_body32<64, true, true>(AT, W, dscale, OutT, M, Np, Na, (int)blockIdx.x * 32,
                                As, Bs);
}

// ---------------------------------------------------------------------------
// Chunked pull body (padded CSR): segments x8, 8-aligned; 8 indices = 1 uint4;
// filler index Np-1 hits the zeroed row. 1-block index lookahead.
// ---------------------------------------------------------------------------
__device__ __forceinline__ float4 pull_body(const int* __restrict__ rowptr,
                                            const ushort_t* __restrict__ colu,
                                            const float4* __restrict__ T,
                                            size_t cb, int v, int j) {
    int p0 = rowptr[v], p1 = rowptr[v + 1];
    float4 acc = T[(cb + v) * 4 + j];  // self row slice
    int nb = (p1 - p0) >> 3;
    if (nb == 0) return acc;

    const uint4* cp = reinterpret_cast<const uint4*>(colu + p0);  // 16B aligned
    uint4 ci = cp[0];
    for (int ib = 0; ib < nb; ib++) {
        bool more = (ib + 1 < nb);
        uint4 cn;
        if (more) cn = cp[ib + 1];   // prefetch next 8 indices
        int n0 = ci.x & 0xFFFF, n1 = ci.x >> 16;
        int n2 = ci.y & 0xFFFF, n3 = ci.y >> 16;
        int n4 = ci.z & 0xFFFF, n5 = ci.z >> 16;
        int n6 = ci.w & 0xFFFF, n7 = ci.w >> 16;
        float4 g0 = T[(cb + n0) * 4 + j];
        float4 g1 = T[(cb + n1) * 4 + j];
        float4 g2 = T[(cb + n2) * 4 + j];
        float4 g3 = T[(cb + n3) * 4 + j];
        float4 g4 = T[(cb + n4) * 4 + j];
        float4 g5 = T[(cb + n5) * 4 + j];
        float4 g6 = T[(cb + n6) * 4 + j];
        float4 g7 = T[(cb + n7) * 4 + j];
        acc.x += ((g0.x + g1.x) + (g2.x + g3.x)) + ((g4.x + g5.x) + (g6.x + g7.x));
        acc.y += ((g0.y + g1.y) + (g2.y + g3.y)) + ((g4.y + g5.y) + (g6.y + g7.y));
        acc.z += ((g0.z + g1.z) + (g2.z + g3.z)) + ((g4.z + g5.z) + (g6.z + g7.z));
        acc.w += ((g0.w + g1.w) + (g2.w + g3.w)) + ((g4.w + g5.w) + (g6.w + g7.w));
        ci = cn;
    }
    return acc;
}

// pull128: blockIdx = g*8 + c -> chunk c (XCD c). Output agg1T CHUNKED [8][N][16].
__global__ __launch_bounds__(256) void pull128c_k(const int* __restrict__ rowptr,
                                                  const ushort_t* __restrict__ colu,
                                                  const float4* __restrict__ hsT,
                                                  const float* __restrict__ dinv,
                                                  const float4* __restrict__ bias4,
                                                  float4* __restrict__ out1T,
                                                  int N, int Np) {
    int c = (int)(blockIdx.x & 7);
    int g = (int)(blockIdx.x >> 3);
    int v = g * 64 + (int)(threadIdx.x >> 2);
    if (v >= N) return;
    int j = threadIdx.x & 3;
    float4 acc = pull_body(rowptr, colu, hsT, (size_t)c * Np, v, j);
    float dv = dinv[v];
    float4 bv = bias4[c * 4 + j];
    out1T[((size_t)c * N + v) * 4 + j] =
        make_float4(fmaf(acc.x, dv, bv.x), fmaf(acc.y, dv, bv.y),
                    fmaf(acc.z, dv, bv.z), fmaf(acc.w, dv, bv.w));
}

// pull64: blockIdx = g*4 + c (slice on XCDs c,c+4). Reads g2T (stride Np),
// writes agg2T CHUNKED [4][N][16].
__global__ __launch_bounds__(256) void pull64c_k(const int* __restrict__ rowptr,
                                                 const ushort_t* __restrict__ colu,
                                                 const float4* __restrict__ g2T,
                                                 const float* __restrict__ dinv,
                                                 const float4* __restrict__ bias4,
                                                 float4* __restrict__ outT,
                                                 int N, int Np) {
    int c = (int)(blockIdx.x & 3);
    int g = (int)(blockIdx.x >> 2);
    int v = g * 64 + (int)(threadIdx.x >> 2);
    if (v >= N) return;
    int j = threadIdx.x & 3;
    float4 acc = pull_body(rowptr, colu, g2T, (size_t)c * Np, v, j);
    float dv = dinv[v];
    float4 bv = bias4[c * 4 + j];
    outT[((size_t)c * N + v) * 4 + j] =
        make_float4(fmaf(acc.x, dv, bv.x), fmaf(acc.y, dv, bv.y),
                    fmaf(acc.z, dv, bv.z), fmaf(acc.w, dv, bv.w));
}

// ---------------------------------------------------------------------------
// logits part: edge-order, chunk c = blockIdx&3; part[c*E+e] coalesced.
// ---------------------------------------------------------------------------
__global__ __launch_bounds__(256) void logits_part_k(const int* __restrict__ src,
                                                     const int* __restrict__ dst,
                                                     const float4* __restrict__ aggT,
                                                     float* __restrict__ part,
                                                     int N, int E) {
    int c = (int)(blockIdx.x & 3);
    int blk = (int)(blockIdx.x >> 2);
    int g = (int)(threadIdx.x >> 2);
    int j = threadIdx.x & 3;
    size_t cb = (size_t)c * N;
    int ebase = blk * 256;

#pragma unroll
    for (int i = 0; i < 4; i++) {
        int e = ebase + i * 64 + g;
        if (e < E) {
            int s = src[e], d = dst[e];
            float4 a = aggT[(cb + s) * 4 + j];
            float4 b = aggT[(cb + d) * 4 + j];
            float t = a.x * b.x + a.y * b.y + a.z * b.z + a.w * b.w;
            t += __shfl_xor(t, 1);
            t += __shfl_xor(t, 2);
            if (j == 0) part[(size_t)c * E + e] = t;
        }
    }
}

// out[e] = sum of 4 chunk partials; coalesced float4 I/O.
__global__ __launch_bounds__(256) void logits_reduce_k(const float* __restrict__ part,
                                                       float* __restrict__ out, int E) {
    int i = blockIdx.x * blockDim.x + threadIdx.x;
    int e4 = E >> 2;
    if (i < e4) {
        const float4* p0 = reinterpret_cast<const float4*>(part);
        const float4* p1 = reinterpret_cast<const float4*>(part + (size_t)E);
        const float4* p2 = reinterpret_cast<const float4*>(part + (size_t)E * 2);
        const float4* p3 = reinterpret_cast<const float4*>(part + (size_t)E * 3);
        float4 a = p0[i], b = p1[i], c = p2[i], d = p3[i];
        float4 o = make_float4((a.x + b.x) + (c.x + d.x), (a.y + b.y) + (c.y + d.y),
                               (a.z + b.z) + (c.z + d.z), (a.w + b.w) + (c.w + d.w));
        reinterpret_cast<float4*>(out)[i] = o;
    }
    if (blockIdx.x == 0 && threadIdx.x < (E & 3)) {
        int e = e4 * 4 + threadIdx.x;
        out[e] = part[e] + part[(size_t)E + e] + part[(size_t)E * 2 + e] +
                 part[(size_t)E * 3 + e];
    }
}

extern "C" void kernel_launch(void* const* d_in, const int* in_sizes, int n_in,
                              void* d_out, int out_size, void* d_ws, size_t ws_size,
                              hipStream_t stream) {
    const float* x  = (const float*)d_in[0];
    const int* ei   = (const int*)d_in[1];   // int32 (harness converts ints)
    const float* W1 = (const float*)d_in[2];
    const float* b1 = (const float*)d_in[3];
    const float* W2 = (const float*)d_in[4];
    const float* b2 = (const float*)d_in[5];
    float* out = (float*)d_out;

    const int N = in_sizes[0] / 128;   // 50000 (< 65535 -> ushort col valid)
    const int E = in_sizes[1] / 2;     // 800000
    const int Np = N + 1;              // gather tables have zeroed filler row N
    const int* src = ei;
    const int* dst = ei + E;

    // ---- workspace ----
    // floats: dinv[50176] | regionA[(N+1)*128] | regionB[N*128]
    //   hsT   = regionA              (chunked [8][Np][16])
    //   g2T   = regionA[0, 4*Np*16)  (chunked [4][Np][16]; hsT dead)
    //   agg2T = regionA + 4*Np*16    (chunked [4][N][16])
    //   agg1T = regionB              (chunked [8][N][16]; dead after gemm2)
    //   part  = regionB              (overlays dead agg1T)
    // ints: cnt[N] | incl[N] | rowptr[N+1] | bsum[256] | rank[E] | colu[E+8N]
    float* ws      = (float*)d_ws;
    float* dinv    = ws;
    float* regionA = ws + 50176;
    float* regionB = regionA + (size_t)Np * 128;
    float* hsT     = regionA;
    float* g2T     = regionA;
    float* agg2T   = regionA + (size_t)4 * Np * 16;
    float* agg1T   = regionB;
    float* part    = regionB;

    int* ibase  = (int*)(regionB + (size_t)N * 128);
    int* cnt    = ibase;
    int* incl   = cnt + N;
    int* rowptr = incl + N;
    int* bsum   = rowptr + (N + 1);
    int* rank   = bsum + 256;
    ushort_t* colu = (ushort_t*)(((uintptr_t)(rank + E) + 15) & ~(uintptr_t)15);

    const int B = 256;
    const int NB = (N + 255) / 256;                  // 196
    const unsigned ng64 = (unsigned)((N + 63) / 64); // 782

    // ---- CSR count (+rank) + scans (padded) ----
    hipMemsetAsync(cnt, 0, (size_t)N * sizeof(int), stream);
    cnt_rank_k<<<(E + B - 1) / B, B, 0, stream>>>(dst, cnt, rank, E);  // 3125 blocks
    scan1_k<<<NB, 256, 0, stream>>>(cnt, incl, bsum, N);
    scan23_k<<<NB, 256, 0, stream>>>(cnt, incl, bsum, rowptr, dinv, colu, N, NB);

    // ---- fused: GEMM1 (hsT chunked, zero filler row) + CSR fill ----
    {
        int gemmBlocks = (N + 31) / 32;              // 1563
        int fillBlocks = (E / 4 + B - 1) / B;        // 782
        gemm1_fill_k<<<gemmBlocks + fillBlocks, 256, 0, stream>>>(
            x, W1, dinv, (float4*)hsT, N, Np, src, dst, rowptr, rank, colu, E,
            gemmBlocks);
    }

    // ---- layer 1 pull (8 chunks x 782 node-groups) -> agg1T CHUNKED ----
    pull128c_k<<<ng64 * 8, 256, 0, stream>>>(rowptr, colu, (const float4*)hsT,
                                             dinv, (const float4*)b1,
                                             (float4*)agg1T, N, Np);

    // ---- layer 2 GEMM (chunked A) -> g2T chunked (zero filler row) ----
    gemm2_k<<<(N + 31) / 32, 256, 0, stream>>>(agg1T, W2, dinv, (float4*)g2T, N, Np, N);

    // ---- layer 2 pull (4 chunks x 782 node-groups) -> agg2T chunked ----
    pull64c_k<<<ng64 * 4, 256, 0, stream>>>(rowptr, colu, (const float4*)g2T,
                                            dinv, (const float4*)b2,
                                            (float4*)agg2T, N, Np);

    // ---- logits: edge-order chunked partials + reduce ----
    {
        unsigned blk = (unsigned)((E + 255) / 256);       // 3125
        logits_part_k<<<blk * 4, 256, 0, stream>>>(src, dst, (const float4*)agg2T,
                                                   part, N, E);
        unsigned rblk = (unsigned)((E / 4 + 255) / 256);  // 782
        logits_reduce_k<<<rblk, 256, 0, stream>>>(part, out, E);
    }
}